// Round 8
// baseline (350.623 us; speedup 1.0000x reference)
//
#include <hip/hip_runtime.h>
#include <hip/hip_bf16.h>
#include <math.h>

#define B_   2
#define S_   2048
#define HID_ 2048
#define H_   16
#define HK_  4
#define D_   128
#define NH_  24          // H + 2*HK
#define QKVN 3072        // NH_ * D_
#define R_   64

typedef __attribute__((ext_vector_type(8))) _Float16 h8;     // 8 fp16 MFMA frag
typedef __attribute__((ext_vector_type(4))) _Float16 h4;     // 4 fp16 (b64)
typedef __attribute__((ext_vector_type(2))) _Float16 h2;
typedef __attribute__((ext_vector_type(4))) float f4;        // MFMA accumulator

// async global->LDS, 16B per lane; LDS dest = wave-uniform base + lane*16
#define GLOAD16(gp, lp) __builtin_amdgcn_global_load_lds(                      \
    (const __attribute__((address_space(1))) void*)(gp),                       \
    (__attribute__((address_space(3))) void*)(lp), 16, 0, 0)

// ---------------------------------------------------------------------------
// fused fp32 -> fp16 conversion of all three operands (one launch).
// ---------------------------------------------------------------------------
__global__ __launch_bounds__(256) void cvt3(
    const float* __restrict__ s0, _Float16* __restrict__ d0, int n0,
    const float* __restrict__ s1, _Float16* __restrict__ d1, int n1,
    const float* __restrict__ s2, _Float16* __restrict__ d2, int n2)
{
    int j = blockIdx.x * 256 + threadIdx.x;
    const float* s; _Float16* d;
    if (j < n0) { s = s0; d = d0; }
    else {
        j -= n0;
        if (j < n1) { s = s1; d = d1; }
        else { j -= n1; if (j >= n2) return; s = s2; d = d2; }
    }
    float4 a = ((const float4*)s)[j * 2];
    float4 b = ((const float4*)s)[j * 2 + 1];
    h8 h;
    h[0] = (_Float16)a.x; h[1] = (_Float16)a.y;
    h[2] = (_Float16)a.z; h[3] = (_Float16)a.w;
    h[4] = (_Float16)b.x; h[5] = (_Float16)b.y;
    h[6] = (_Float16)b.z; h[7] = (_Float16)b.w;
    ((h8*)d)[j] = h;
}

// ---------------------------------------------------------------------------
// QKV projection GEMM, BM=256 x BN=128 tile, 512 threads (8 waves, 4M x 2N,
// wave tile 64x64), BK=64, K-tile double-buffered global_load_lds staging
// with both-sides XOR swizzle. 2x output per block vs 128^2 -> halves
// per-output staging traffic and barrier-drain stalls (round-6: MfmaUtil 23%,
// ~5000 cyc/iter drain). LDS 98 KB -> 1 block/CU, latency hidden by dbuf.
// FUSED epilogue: RMSNorm + RoPE + V-transpose.
//   h in [0,16)  -> Qh fp16, pre-scaled by 1/sqrt(128)*log2(e)
//   h in [16,20) -> Kh fp16
//   h in [20,24) -> Vt fp16 (B*HK, D, S)
// ---------------------------------------------------------------------------
__global__ __launch_bounds__(512) void gemm_qkv(
    const _Float16* __restrict__ A, const _Float16* __restrict__ Bm,
    const float* __restrict__ cosT, const float* __restrict__ sinT,
    const float* __restrict__ qw, const float* __restrict__ kw,
    _Float16* __restrict__ Qh_g, _Float16* __restrict__ Kh_g,
    _Float16* __restrict__ Vt_g)
{
    __shared__ _Float16 Ast[2][256][64];      // 64 KB
    __shared__ _Float16 Bst[2][128][64];      // 32 KB
    __shared__ float exch[2][256];            // 2 KB

    const int tid = threadIdx.x;
    const int wave = tid >> 6, lane = tid & 63;
    const int l15 = lane & 15, l4 = lane >> 4;
    const int h  = blockIdx.x;            // head 0..23
    const int m0 = blockIdx.y * 256;      // token block
    const int n0 = h * 128;
    const int wm = (wave >> 1) * 64, wn = (wave & 1) * 64;
    const int K = HID_;

    f4 acc[16];
#pragma unroll
    for (int t = 0; t < 16; ++t) acc[t] = (f4){0.f, 0.f, 0.f, 0.f};

    const int srow = lane >> 3;                    // row within 8-row chunk
    const int scol = ((lane & 7) ^ srow) * 8;      // inverse-swizzled source col
    const int sw   = l15 & 7;                      // read-side row swizzle key

    auto STAGE = [&](int bf, int k0) {
#pragma unroll
        for (int t = 0; t < 4; ++t) {
            const int chunk = wave * 4 + t;        // 0..31 (8 rows each)
            const int grow  = chunk * 8 + srow;    // 0..255
            GLOAD16(A + (size_t)(m0 + grow) * K + k0 + scol, &Ast[bf][chunk * 8][0]);
        }
#pragma unroll
        for (int t = 0; t < 2; ++t) {
            const int chunk = wave * 2 + t;        // 0..15
            const int grow  = chunk * 8 + srow;    // 0..127
            GLOAD16(Bm + (size_t)(n0 + grow) * K + k0 + scol, &Bst[bf][chunk * 8][0]);
        }
    };

    STAGE(0, 0);
    int cur = 0;

    for (int k0 = 0; k0 < K; k0 += 64) {
        __syncthreads();   // vmcnt(0): tile-k0 landed; all prev-buf reads done
        if (k0 + 64 < K) STAGE(cur ^ 1, k0 + 64);   // overlaps this compute

#pragma unroll
        for (int j = 0; j < 2; ++j) {
            h8 ahf[4], bhf[4];
#pragma unroll
            for (int i = 0; i < 4; ++i) {
                ahf[i] = *(const h8*)&Ast[cur][wm + i * 16 + l15][((j * 4 + l4) ^ sw) * 8];
                bhf[i] = *(const h8*)&Bst[cur][wn + i * 16 + l15][((j * 4 + l4) ^ sw) * 8];
            }
            __builtin_amdgcn_s_setprio(1);
#pragma unroll
            for (int i = 0; i < 4; ++i)
#pragma unroll
                for (int jj = 0; jj < 4; ++jj)
                    acc[i * 4 + jj] = __builtin_amdgcn_mfma_f32_16x16x32_f16(
                        ahf[i], bhf[jj], acc[i * 4 + jj], 0, 0, 0);
            __builtin_amdgcn_s_setprio(0);
        }
        cur ^= 1;
    }

    // ---------------- fused epilogue ----------------
    // acc[i*4+jj][r]: token row = m0 + wm + i*16 + l4*4 + r (wm in {0,64,128,192})
    //                 col (d)   = wn + jj*16 + l15          (wn in {0,64})
    const int bb = m0 >> 11;              // batch (S_=2048, m0 mult of 256)
    const int s0 = m0 & 2047;             // seq base

    if (h < 20) {
        // ---- RMS sum of squares over full d=0..127 per token row ----
        float sq[4][4];                   // [i][r]
#pragma unroll
        for (int i = 0; i < 4; ++i)
#pragma unroll
            for (int r = 0; r < 4; ++r) {
                float s = 0.f;
#pragma unroll
                for (int jj = 0; jj < 4; ++jj) {
                    float v = acc[i * 4 + jj][r];
                    s += v * v;
                }
                s += __shfl_xor(s, 1);
                s += __shfl_xor(s, 2);
                s += __shfl_xor(s, 4);
                s += __shfl_xor(s, 8);    // sum over this wave's 64 cols
                sq[i][r] = s;
            }
        const int half = wave & 1;        // wn index
        if (l15 == 0) {
#pragma unroll
            for (int i = 0; i < 4; ++i)
#pragma unroll
                for (int r = 0; r < 4; ++r)
                    exch[half][wm + i * 16 + l4 * 4 + r] = sq[i][r];
        }
        __syncthreads();                  // exch ready; main-loop LDS reads done

        const float* wln = (h < 16) ? qw : kw;
        float wv[4];
#pragma unroll
        for (int jj = 0; jj < 4; ++jj) wv[jj] = wln[wn + jj * 16 + l15];

        const float QS = 0.08838834764831845f * 1.4426950408889634f;
        // bounce buffer: [256 tokens][128 d] fp16 = 64 KB, overlays Ast dbuf
        _Float16 (*Ld)[128] = (_Float16 (*)[128])&Ast[0][0][0];

#pragma unroll
        for (int i = 0; i < 4; ++i) {
#pragma unroll
            for (int r = 0; r < 4; ++r) {
                const int row = wm + i * 16 + l4 * 4 + r;
                const int s  = s0 + row;
                float tot = sq[i][r] + exch[half ^ 1][row];
                float scale = rsqrtf(tot * (1.f / 128.f) + 1e-6f);
                float y[4];
#pragma unroll
                for (int jj = 0; jj < 4; ++jj)
                    y[jj] = acc[i * 4 + jj][r] * scale * wv[jj];

                float yr[4];
                if (wn == 0) {            // d < 64: RoPE rotates
                    const float* cp = cosT + ((size_t)bb * S_ + s) * R_;
                    const float* sp = sinT + ((size_t)bb * S_ + s) * R_;
                    float cs[4], sn[4];
#pragma unroll
                    for (int jj = 0; jj < 4; ++jj) {
                        cs[jj] = cp[jj * 16 + l15];
                        sn[jj] = sp[jj * 16 + l15];
                    }
                    yr[0] = y[0] * cs[0] - y[2] * sn[0];
                    yr[1] = y[1] * cs[1] - y[3] * sn[1];
                    yr[2] = y[2] * cs[2] + y[0] * sn[2];
                    yr[3] = y[3] * cs[3] + y[1] * sn[3];
                } else {                  // d >= 64: pass-through
#pragma unroll
                    for (int jj = 0; jj < 4; ++jj) yr[jj] = y[jj];
                }

                const float os = (h < 16) ? QS : 1.f;
#pragma unroll
                for (int jj = 0; jj < 4; ++jj)
                    Ld[row][wn + jj * 16 + l15] = (_Float16)(yr[jj] * os);
            }
        }
        __syncthreads();                  // bounce buffer complete

        // ---- coalesced b128 stores: 32 rows per pass, full 256B rows ----
        _Float16* outb = (h < 16)
            ? Qh_g + (((size_t)bb * H_ + h) * S_ + s0) * D_
            : Kh_g + (((size_t)bb * HK_ + (h - 16)) * S_ + s0) * D_;
        const int rr = tid >> 4;          // 0..31
        const int d0 = (tid & 15) * 8;    // 0..120
#pragma unroll
        for (int it = 0; it < 8; ++it) {
            const int row = it * 32 + rr;
            *(h8*)(outb + (size_t)row * D_ + d0) = *(const h8*)&Ld[row][d0];
        }
    } else {
        // ---- V head: transposed write, 4 consecutive tokens per b64 ----
        const size_t vbase = ((size_t)bb * HK_ + (h - 20)) * D_ * S_;
#pragma unroll
        for (int i = 0; i < 4; ++i)
#pragma unroll
            for (int jj = 0; jj < 4; ++jj) {
                h4 pk;
#pragma unroll
                for (int r = 0; r < 4; ++r) pk[r] = (_Float16)acc[i * 4 + jj][r];
                const int d = wn + jj * 16 + l15;
                const int s = s0 + wm + i * 16 + l4 * 4;
                *(h4*)(Vt_g + vbase + (size_t)d * S_ + s) = pk;
            }
    }
}

// ---------------------------------------------------------------------------
// Dense projection GEMM, BM=256 x BN=128, 512 threads, K-tile dbuf.
// Grid = 16x16 = 256 blocks = exactly 1/CU. fp32 out.
// ---------------------------------------------------------------------------
__global__ __launch_bounds__(512) void gemm_dense(
    const _Float16* __restrict__ A, const _Float16* __restrict__ Bm,
    float* __restrict__ Cv, int M, int N, int K)
{
    __shared__ _Float16 Ast[2][256][64];      // 64 KB
    __shared__ _Float16 Bst[2][128][64];      // 32 KB

    const int tid = threadIdx.x;
    const int wave = tid >> 6, lane = tid & 63;
    const int l15 = lane & 15, l4 = lane >> 4;
    const int m0 = blockIdx.y * 256, n0 = blockIdx.x * 128;
    const int wm = (wave >> 1) * 64, wn = (wave & 1) * 64;

    f4 acc[16];
#pragma unroll
    for (int t = 0; t < 16; ++t) acc[t] = (f4){0.f, 0.f, 0.f, 0.f};

    const int srow = lane >> 3;
    const int scol = ((lane & 7) ^ srow) * 8;
    const int sw   = l15 & 7;

    auto STAGE = [&](int bf, int k0) {
#pragma unroll
        for (int t = 0; t < 4; ++t) {
            const int chunk = wave * 4 + t;        // 0..31
            const int grow  = chunk * 8 + srow;
            GLOAD16(A + (size_t)(m0 + grow) * K + k0 + scol, &Ast[bf][chunk * 8][0]);
        }
#pragma unroll
        for (int t = 0; t < 2; ++t) {
            const int chunk = wave * 2 + t;        // 0..15
            const int grow  = chunk * 8 + srow;
            GLOAD16(Bm + (size_t)(n0 + grow) * K + k0 + scol, &Bst[bf][chunk * 8][0]);
        }
    };

    STAGE(0, 0);
    int cur = 0;

    for (int k0 = 0; k0 < K; k0 += 64) {
        __syncthreads();   // vmcnt(0): tile-k0 landed; all prev-buf reads done
        if (k0 + 64 < K) STAGE(cur ^ 1, k0 + 64);

#pragma unroll
        for (int j = 0; j < 2; ++j) {
            h8 ahf[4], bhf[4];
#pragma unroll
            for (int i = 0; i < 4; ++i) {
                ahf[i] = *(const h8*)&Ast[cur][wm + i * 16 + l15][((j * 4 + l4) ^ sw) * 8];
                bhf[i] = *(const h8*)&Bst[cur][wn + i * 16 + l15][((j * 4 + l4) ^ sw) * 8];
            }
            __builtin_amdgcn_s_setprio(1);
#pragma unroll
            for (int i = 0; i < 4; ++i)
#pragma unroll
                for (int jj = 0; jj < 4; ++jj)
                    acc[i * 4 + jj] = __builtin_amdgcn_mfma_f32_16x16x32_f16(
                        ahf[i], bhf[jj], acc[i * 4 + jj], 0, 0, 0);
            __builtin_amdgcn_s_setprio(0);
        }
        cur ^= 1;
    }

#pragma unroll
    for (int i = 0; i < 4; ++i)
#pragma unroll
        for (int jj = 0; jj < 4; ++jj)
#pragma unroll
            for (int r = 0; r < 4; ++r) {
                int row = m0 + wm + i * 16 + l4 * 4 + r;
                int col = n0 + wn + jj * 16 + l15;
                Cv[(size_t)row * N + col] = acc[i * 4 + jj][r];
            }
}

// ---------------------------------------------------------------------------
// MFMA flash attention (round-3/5 version, single dispatch): all-fp16,
// fixed-shift softmax (exp2(s-8), bias in MFMA C-in), flat q-split,
// K/V double-buffered via global_load_lds, 16B-granule XOR swizzle.
// LDS-pipe-bound at ~90% of structural roofline (~91 us) — left unchanged.
// ---------------------------------------------------------------------------
__global__ __launch_bounds__(256, 2) void flash_mfma(
    const _Float16* __restrict__ Qh_g, const _Float16* __restrict__ Kh_g,
    const _Float16* __restrict__ Vt_g, _Float16* __restrict__ Ao)
{
    __shared__ _Float16 Ksh[2][64][128];   // [buf][kv][d], granule-swizzled
    __shared__ _Float16 Vsh[2][128][64];   // [buf][d][kv], granule-swizzled
    __shared__ _Float16 Ps [128][64];      // [q][kv], granule-swizzled

    const int tid = threadIdx.x;
    const int wave = tid >> 6, lane = tid & 63;
    const int l15 = lane & 15, l4 = lane >> 4;
    const int qb = blockIdx.x, h = blockIdx.y, b = blockIdx.z;
    const int kh = h >> 2;
    const int key = l15 & 7;            // read-side swizzle key (row&7)

    // ---- Q fragments: direct fp16 loads (pre-scaled in gemm_qkv) ----
    h8 qf[2][4];
#pragma unroll
    for (int i = 0; i < 2; ++i) {
        const _Float16* qrow = Qh_g +
            (((size_t)b * H_ + h) * S_ + qb * 128 + wave * 32 + i * 16 + l15) * D_;
#pragma unroll
        for (int j = 0; j < 4; ++j)
            qf[i][j] = *(const h8*)(qrow + j * 32 + l4 * 8);
    }

    f4 o[2][8];
#pragma unroll
    for (int i = 0; i < 2; ++i)
#pragma unroll
        for (int t = 0; t < 8; ++t) o[i][t] = (f4){0.f, 0.f, 0.f, 0.f};
    float l_part[2] = {0.f, 0.f};

    const size_t kvoff = ((size_t)b * HK_ + kh) * S_ * D_;
    const _Float16* kg = Kh_g + kvoff;   // (S, D)
    const _Float16* vg = Vt_g + kvoff;   // (D, S)

    int krow[4], ksrc[4], vrow[4], vsrc[4];
#pragma unroll
    for (int t = 0; t < 4; ++t) {
        krow[t] = wave * 16 + t * 4 + (lane >> 4);            // kv row 0..63
        ksrc[t] = ((lane & 15) ^ (krow[t] & 7)) * 8;          // inv-swz col
        vrow[t] = wave * 32 + t * 8 + (lane >> 3);            // d row 0..127
        vsrc[t] = ((lane & 7) ^ (vrow[t] & 7)) * 8;           // inv-swz col
    }

    auto STAGE = [&](int bf, int kb) {
#pragma unroll
        for (int t = 0; t < 4; ++t)
            GLOAD16(kg + (size_t)(kb * 64 + krow[t]) * D_ + ksrc[t],
                    &Ksh[bf][wave * 16 + t * 4][0]);
#pragma unroll
        for (int t = 0; t < 4; ++t)
            GLOAD16(vg + (size_t)vrow[t] * S_ + kb * 64 + vsrc[t],
                    &Vsh[bf][wave * 32 + t * 8][0]);
    };

    STAGE(0, 0);
    int cur = 0;

    for (int kb = 0; kb < S_ / 64; ++kb) {
        __syncthreads();   // vmcnt(0): tile-kb stage landed; all prev reads done
        if (kb + 1 < S_ / 64) STAGE(cur ^ 1, kb + 1);   // overlaps this compute

        // ---- QK^T swapped: acc[c][i] -> q = l15 (+i*16), kv = c*16+l4*4+r ----
        f4 acc[4][2];
#pragma unroll
        for (int c = 0; c < 4; ++c)
#pragma unroll
            for (int i = 0; i < 2; ++i)
                acc[c][i] = (f4){-8.f, -8.f, -8.f, -8.f};   // exp2 bias in C-in
#pragma unroll
        for (int j = 0; j < 4; ++j) {
#pragma unroll
            for (int c = 0; c < 4; ++c) {
                h8 kf = *(const h8*)&Ksh[cur][c * 16 + l15][((j * 4 + l4) ^ key) * 8];
#pragma unroll
                for (int i = 0; i < 2; ++i)
                    acc[c][i] = __builtin_amdgcn_mfma_f32_16x16x32_f16(
                        kf, qf[i][j], acc[c][i], 0, 0, 0);
            }
        }

        // ---- exp2 + swizzled b64 P-store (rows wave-local, no barrier) ----
#pragma unroll
        for (int c = 0; c < 4; ++c) {
#pragma unroll
            for (int i = 0; i < 2; ++i) {
                h4 pk;
#pragma unroll
                for (int r = 0; r < 4; ++r) {
                    float e_ = exp2f(acc[c][i][r]);
                    l_part[i] += e_;
                    pk[r] = (_Float16)e_;
                }
                int g = 2 * c + (l4 >> 1);                    // 16B granule
                *(h4*)&Ps[wave * 32 + i * 16 + l15][(g ^ key) * 8 + (l4 & 1) * 4] = pk;
            }
        }

        // ---- PV ----
#pragma unroll
        for (int s2 = 0; s2 < 2; ++s2) {
            int gc = ((s2 * 4 + l4) ^ key) * 8;
            h8 pf0 = *(const h8*)&Ps[wave * 32 + l15][gc];
            h8 pf1 = *(const h8*)&Ps[wave * 32 + 16 + l15][gc];
#pragma unroll
            for (int t = 0; t < 8; ++t) {
                h8 vf = *(const h8*)&Vsh[cur][t * 16 + l15][gc];
                o[0][t] = __builtin_amdgcn_mfma_f32_16x16x32_f16(pf0, vf, o[0][t], 0, 0, 0);
                o[1][t] = __builtin_amdgcn_mfma_f32_16x16x32_f16(pf1, vf, o[1][t], 0, 0, 0);
            }
        }
        cur ^= 1;
    }

    // ---- softmax denominator (q = i*16 + l15), broadcast to C-layout rows ----
    float Linv[2];
#pragma unroll
    for (int i = 0; i < 2; ++i) {
        float l = l_part[i];
        l += __shfl_xor(l, 16);
        l += __shfl_xor(l, 32);
        Linv[i] = 1.f / l;
    }
#pragma unroll
    for (int i = 0; i < 2; ++i) {
        float inv[4];
#pragma unroll
        for (int r = 0; r < 4; ++r) inv[r] = __shfl(Linv[i], l4 * 4 + r);
#pragma unroll
        for (int t = 0; t < 8; ++t) {
#pragma unroll
            for (int r = 0; r < 4; ++r) {
                int row = qb * 128 + wave * 32 + i * 16 + l4 * 4 + r;
                Ao[((size_t)b * S_ + row) * (H_ * D_) + h * D_ + t * 16 + l15] =
                    (_Float16)(o[i][t][r] * inv[r]);
            }
        }
    }
}

// ---------------------------------------------------------------------------
extern "C" void kernel_launch(void* const* d_in, const int* in_sizes, int n_in,
                              void* d_out, int out_size, void* d_ws, size_t ws_size,
                              hipStream_t stream)
{
    const float* hidden  = (const float*)d_in[0];
    const float* cosT    = (const float*)d_in[1];
    const float* sinT    = (const float*)d_in[2];
    const float* w_qkv   = (const float*)d_in[3];
    const float* q_ln    = (const float*)d_in[4];
    const float* k_ln    = (const float*)d_in[5];
    const float* w_dense = (const float*)d_in[6];
    float* out = (float*)d_out;

    // workspace layout (bytes), NO aliasing (gemm_qkv writes Qh/Kh/Vt while
    // reading hidden16/wqkv16):
    //   attn16   : 16,777,216  @ 0
    //   hidden16 : 16,777,216  @ 16,777,216
    //   wqkv16   : 12,582,912  @ 33,554,432
    //   Qh       : 16,777,216  @ 46,137,344
    //   Kh       :  4,194,304  @ 62,914,560
    //   Vt       :  4,194,304  @ 67,108,864
    //   wdense16 :  8,388,608  @ 71,303,168
    // total 79,691,776
    char* w = (char*)d_ws;
    _Float16* attn16   = (_Float16*)w;
    _Float16* hidden16 = (_Float16*)(w + 16777216);
    _Float16* wqkv16   = (_Float16*)(w + 33554432);
    _Float16* Qh       = (_Float16*)(w + 46137344);
    _Float16* Kh       = (_Float16*)(w + 62914560);
    _Float16* Vt       = (_Float16*)(w + 67108864);
    _Float16* wdense16 = (_Float16*)(w + 71303168);

    // 0) fp32 -> fp16 operand conversions (single fused launch)
    cvt3<<<9216, 256, 0, stream>>>(hidden,  hidden16, 1048576,
                                   w_qkv,   wqkv16,   786432,
                                   w_dense, wdense16, 524288);

    // 1) QKV projection with fused RMSNorm+RoPE+V-transpose epilogue
    //    grid: 24 heads x 16 token-blocks of 256, 512 threads
    gemm_qkv<<<dim3(NH_, (B_ * S_) / 256), 512, 0, stream>>>(
        hidden16, wqkv16, cosT, sinT, q_ln, k_ln, Qh, Kh, Vt);

    // 2) MFMA flash attention -> attn16 (B,S,H*D) fp16  (single dispatch)
    flash_mfma<<<dim3(S_ / 128, H_, B_), 256, 0, stream>>>(Qh, Kh, Vt, attn16);

    // 3) dense projection (fp16 MFMA GEMM, fp32 out), 256 blocks = 1/CU
    gemm_dense<<<dim3(HID_ / 128, (B_ * S_) / 256), 512, 0, stream>>>(
        attn16, wdense16, out, B_ * S_, HID_, H_ * D_);
}

// Round 9
// 321.728 us; speedup vs baseline: 1.0898x; 1.0898x over previous
//
#include <hip/hip_runtime.h>
#include <hip/hip_bf16.h>
#include <math.h>

#define B_   2
#define S_   2048
#define HID_ 2048
#define H_   16
#define HK_  4
#define D_   128
#define NH_  24          // H + 2*HK
#define QKVN 3072        // NH_ * D_
#define R_   64

typedef __attribute__((ext_vector_type(8))) _Float16 h8;     // 8 fp16 MFMA frag
typedef __attribute__((ext_vector_type(4))) _Float16 h4;     // 4 fp16 (b64)
typedef __attribute__((ext_vector_type(2))) _Float16 h2;
typedef __attribute__((ext_vector_type(4))) float f4;        // MFMA accumulator

// async global->LDS, 16B per lane; LDS dest = wave-uniform base + lane*16
#define GLOAD16(gp, lp) __builtin_amdgcn_global_load_lds(                      \
    (const __attribute__((address_space(1))) void*)(gp),                       \
    (__attribute__((address_space(3))) void*)(lp), 16, 0, 0)

// ---------------------------------------------------------------------------
// fused fp32 -> fp16 conversion of all three operands (one launch).
// ---------------------------------------------------------------------------
__global__ __launch_bounds__(256) void cvt3(
    const float* __restrict__ s0, _Float16* __restrict__ d0, int n0,
    const float* __restrict__ s1, _Float16* __restrict__ d1, int n1,
    const float* __restrict__ s2, _Float16* __restrict__ d2, int n2)
{
    int j = blockIdx.x * 256 + threadIdx.x;
    const float* s; _Float16* d;
    if (j < n0) { s = s0; d = d0; }
    else {
        j -= n0;
        if (j < n1) { s = s1; d = d1; }
        else { j -= n1; if (j >= n2) return; s = s2; d = d2; }
    }
    float4 a = ((const float4*)s)[j * 2];
    float4 b = ((const float4*)s)[j * 2 + 1];
    h8 h;
    h[0] = (_Float16)a.x; h[1] = (_Float16)a.y;
    h[2] = (_Float16)a.z; h[3] = (_Float16)a.w;
    h[4] = (_Float16)b.x; h[5] = (_Float16)b.y;
    h[6] = (_Float16)b.z; h[7] = (_Float16)b.w;
    ((h8*)d)[j] = h;
}

// ---------------------------------------------------------------------------
// QKV projection GEMM, 128x128 tile, BK=32, K-tile DOUBLE-BUFFERED, 256 thr
// (4 waves, 2x2 of 64x64). LDS 34 KB -> 4 blocks/CU: inter-block TLP absorbs
// barrier/drain stalls (round-8 lesson: 1 block/CU is pathological; round-6:
// stall ~8x work at low TLP). Granule swizzle for 64B rows: physical granule
// = logical ^ (row&3); staged with inverse-swizzled GLOBAL source, linear
// LDS dest; reads apply the same XOR (both-sides-or-neither).
// FUSED epilogue: RMSNorm + RoPE + V-transpose.
//   h in [0,16)  -> Qh fp16, pre-scaled by 1/sqrt(128)*log2(e)
//   h in [16,20) -> Kh fp16
//   h in [20,24) -> Vt fp16 (B*HK, D, S)
// ---------------------------------------------------------------------------
__global__ __launch_bounds__(256, 4) void gemm_qkv(
    const _Float16* __restrict__ A, const _Float16* __restrict__ Bm,
    const float* __restrict__ cosT, const float* __restrict__ sinT,
    const float* __restrict__ qw, const float* __restrict__ kw,
    _Float16* __restrict__ Qh_g, _Float16* __restrict__ Kh_g,
    _Float16* __restrict__ Vt_g)
{
    __shared__ char smem_raw[34816];                         // 34 KB
    auto Ast  = (_Float16 (*)[128][32])(smem_raw);           // [2][128][32]
    auto Bst  = (_Float16 (*)[128][32])(smem_raw + 16384);   // [2][128][32]
    auto exch = (float (*)[128])(smem_raw + 32768);          // [2][128]

    const int tid = threadIdx.x;
    const int wave = tid >> 6, lane = tid & 63;
    const int l15 = lane & 15, l4 = lane >> 4;
    const int h  = blockIdx.x;            // head 0..23
    const int m0 = blockIdx.y * 128;      // token block
    const int n0 = h * 128;
    const int wm = (wave >> 1) * 64, wn = (wave & 1) * 64;
    const int K = HID_;

    f4 acc[16];
#pragma unroll
    for (int t = 0; t < 16; ++t) acc[t] = (f4){0.f, 0.f, 0.f, 0.f};

    // staging: per lane, rows lane>>2 within wave's 16-row strip; inverse-
    // swizzled source granule (XOR row&3)
    const int srow = lane >> 2;                              // 0..15
    const int gsrc = (((lane & 3) ^ (srow & 3)) * 8);        // halfs
    const int rkey = l15 & 3;                                // read swizzle key

    auto STAGE = [&](int bf, int k0) {
#pragma unroll
        for (int t = 0; t < 2; ++t) {
            const int rbase = wave * 16 + 64 * t;            // wave-uniform
            const int grow  = rbase + srow;
            GLOAD16(A  + (size_t)(m0 + grow) * K + k0 + gsrc, &Ast[bf][rbase][0]);
            GLOAD16(Bm + (size_t)(n0 + grow) * K + k0 + gsrc, &Bst[bf][rbase][0]);
        }
    };

    STAGE(0, 0);
    int cur = 0;

    for (int k0 = 0; k0 < K; k0 += 32) {
        __syncthreads();   // vmcnt(0): tile-k0 landed; prev-buf reads done
        if (k0 + 32 < K) STAGE(cur ^ 1, k0 + 32);   // overlaps this compute

        h8 ahf[4], bhf[4];
#pragma unroll
        for (int i = 0; i < 4; ++i) {
            ahf[i] = *(const h8*)&Ast[cur][wm + i * 16 + l15][(l4 ^ rkey) * 8];
            bhf[i] = *(const h8*)&Bst[cur][wn + i * 16 + l15][(l4 ^ rkey) * 8];
        }
        __builtin_amdgcn_s_setprio(1);
#pragma unroll
        for (int i = 0; i < 4; ++i)
#pragma unroll
            for (int jj = 0; jj < 4; ++jj)
                acc[i * 4 + jj] = __builtin_amdgcn_mfma_f32_16x16x32_f16(
                    ahf[i], bhf[jj], acc[i * 4 + jj], 0, 0, 0);
        __builtin_amdgcn_s_setprio(0);
        cur ^= 1;
    }

    // ---------------- fused epilogue ----------------
    // acc[i*4+jj][r]: token row = m0 + wm + i*16 + l4*4 + r
    //                 col (d)   = wn + jj*16 + l15
    const int bb = m0 >> 11;              // batch (S_=2048, m0 mult of 128)
    const int s0 = m0 & 2047;             // seq base

    if (h < 20) {
        // ---- RMS sum of squares over full d=0..127 per token row ----
        float sq[4][4];                   // [i][r]
#pragma unroll
        for (int i = 0; i < 4; ++i)
#pragma unroll
            for (int r = 0; r < 4; ++r) {
                float s = 0.f;
#pragma unroll
                for (int jj = 0; jj < 4; ++jj) {
                    float v = acc[i * 4 + jj][r];
                    s += v * v;
                }
                s += __shfl_xor(s, 1);
                s += __shfl_xor(s, 2);
                s += __shfl_xor(s, 4);
                s += __shfl_xor(s, 8);    // sum over this wave's 64 cols
                sq[i][r] = s;
            }
        const int half = wave & 1;        // wn index
        if (l15 == 0) {
#pragma unroll
            for (int i = 0; i < 4; ++i)
#pragma unroll
                for (int r = 0; r < 4; ++r)
                    exch[half][wm + i * 16 + l4 * 4 + r] = sq[i][r];
        }
        __syncthreads();                  // exch ready; main-loop LDS reads done

        const float* wln = (h < 16) ? qw : kw;
        float wv[4];
#pragma unroll
        for (int jj = 0; jj < 4; ++jj) wv[jj] = wln[wn + jj * 16 + l15];

        const float QS = 0.08838834764831845f * 1.4426950408889634f;
        // bounce buffer: [128 tokens][128 d] fp16 = 32 KB, overlays Ast/Bst
        _Float16 (*Ld)[128] = (_Float16 (*)[128])smem_raw;

#pragma unroll
        for (int i = 0; i < 4; ++i) {
#pragma unroll
            for (int r = 0; r < 4; ++r) {
                const int row = wm + i * 16 + l4 * 4 + r;
                const int s  = s0 + row;
                float tot = sq[i][r] + exch[half ^ 1][row];
                float scale = rsqrtf(tot * (1.f / 128.f) + 1e-6f);
                float y[4];
#pragma unroll
                for (int jj = 0; jj < 4; ++jj)
                    y[jj] = acc[i * 4 + jj][r] * scale * wv[jj];

                float yr[4];
                if (wn == 0) {            // d < 64: RoPE rotates
                    const float* cp = cosT + ((size_t)bb * S_ + s) * R_;
                    const float* sp = sinT + ((size_t)bb * S_ + s) * R_;
                    float cs[4], sn[4];
#pragma unroll
                    for (int jj = 0; jj < 4; ++jj) {
                        cs[jj] = cp[jj * 16 + l15];
                        sn[jj] = sp[jj * 16 + l15];
                    }
                    yr[0] = y[0] * cs[0] - y[2] * sn[0];
                    yr[1] = y[1] * cs[1] - y[3] * sn[1];
                    yr[2] = y[2] * cs[2] + y[0] * sn[2];
                    yr[3] = y[3] * cs[3] + y[1] * sn[3];
                } else {                  // d >= 64: pass-through
#pragma unroll
                    for (int jj = 0; jj < 4; ++jj) yr[jj] = y[jj];
                }

                const float os = (h < 16) ? QS : 1.f;
#pragma unroll
                for (int jj = 0; jj < 4; ++jj)
                    Ld[row][wn + jj * 16 + l15] = (_Float16)(yr[jj] * os);
            }
        }
        __syncthreads();                  // bounce buffer complete

        // ---- coalesced b128 stores: 16 rows per pass, full 256B rows ----
        _Float16* outb = (h < 16)
            ? Qh_g + (((size_t)bb * H_ + h) * S_ + s0) * D_
            : Kh_g + (((size_t)bb * HK_ + (h - 16)) * S_ + s0) * D_;
        const int rr = tid >> 4;          // 0..15
        const int d0 = (tid & 15) * 8;    // 0..120
#pragma unroll
        for (int it = 0; it < 8; ++it) {
            const int row = it * 16 + rr;
            *(h8*)(outb + (size_t)row * D_ + d0) = *(const h8*)&Ld[row][d0];
        }
    } else {
        // ---- V head: transposed write, 4 consecutive tokens per b64 ----
        const size_t vbase = ((size_t)bb * HK_ + (h - 20)) * D_ * S_;
#pragma unroll
        for (int i = 0; i < 4; ++i)
#pragma unroll
            for (int jj = 0; jj < 4; ++jj) {
                h4 pk;
#pragma unroll
                for (int r = 0; r < 4; ++r) pk[r] = (_Float16)acc[i * 4 + jj][r];
                const int d = wn + jj * 16 + l15;
                const int s = s0 + wm + i * 16 + l4 * 4;
                *(h4*)(Vt_g + vbase + (size_t)d * S_ + s) = pk;
            }
    }
}

// ---------------------------------------------------------------------------
// Dense projection GEMM, 128x128 tile, BK=32 dbuf, 256 thr, LDS 32 KB ->
// 4+ blocks/CU; grid 512 = 2/CU fully co-resident. fp32 out.
// ---------------------------------------------------------------------------
__global__ __launch_bounds__(256, 4) void gemm_dense(
    const _Float16* __restrict__ A, const _Float16* __restrict__ Bm,
    float* __restrict__ Cv, int M, int N, int K)
{
    __shared__ _Float16 Ast[2][128][32];      // 16 KB
    __shared__ _Float16 Bst[2][128][32];      // 16 KB

    const int tid = threadIdx.x;
    const int wave = tid >> 6, lane = tid & 63;
    const int l15 = lane & 15, l4 = lane >> 4;
    const int m0 = blockIdx.y * 128, n0 = blockIdx.x * 128;
    const int wm = (wave >> 1) * 64, wn = (wave & 1) * 64;

    f4 acc[16];
#pragma unroll
    for (int t = 0; t < 16; ++t) acc[t] = (f4){0.f, 0.f, 0.f, 0.f};

    const int srow = lane >> 2;
    const int gsrc = (((lane & 3) ^ (srow & 3)) * 8);
    const int rkey = l15 & 3;

    auto STAGE = [&](int bf, int k0) {
#pragma unroll
        for (int t = 0; t < 2; ++t) {
            const int rbase = wave * 16 + 64 * t;
            const int grow  = rbase + srow;
            GLOAD16(A  + (size_t)(m0 + grow) * K + k0 + gsrc, &Ast[bf][rbase][0]);
            GLOAD16(Bm + (size_t)(n0 + grow) * K + k0 + gsrc, &Bst[bf][rbase][0]);
        }
    };

    STAGE(0, 0);
    int cur = 0;

    for (int k0 = 0; k0 < K; k0 += 32) {
        __syncthreads();   // vmcnt(0): tile-k0 landed; prev-buf reads done
        if (k0 + 32 < K) STAGE(cur ^ 1, k0 + 32);

        h8 ahf[4], bhf[4];
#pragma unroll
        for (int i = 0; i < 4; ++i) {
            ahf[i] = *(const h8*)&Ast[cur][wm + i * 16 + l15][(l4 ^ rkey) * 8];
            bhf[i] = *(const h8*)&Bst[cur][wn + i * 16 + l15][(l4 ^ rkey) * 8];
        }
        __builtin_amdgcn_s_setprio(1);
#pragma unroll
        for (int i = 0; i < 4; ++i)
#pragma unroll
            for (int jj = 0; jj < 4; ++jj)
                acc[i * 4 + jj] = __builtin_amdgcn_mfma_f32_16x16x32_f16(
                    ahf[i], bhf[jj], acc[i * 4 + jj], 0, 0, 0);
        __builtin_amdgcn_s_setprio(0);
        cur ^= 1;
    }

#pragma unroll
    for (int i = 0; i < 4; ++i)
#pragma unroll
        for (int jj = 0; jj < 4; ++jj)
#pragma unroll
            for (int r = 0; r < 4; ++r) {
                int row = m0 + wm + i * 16 + l4 * 4 + r;
                int col = n0 + wn + jj * 16 + l15;
                Cv[(size_t)row * N + col] = acc[i * 4 + jj][r];
            }
}

// ---------------------------------------------------------------------------
// MFMA flash attention (round-3/5/7 version, unchanged): all-fp16,
// fixed-shift softmax (exp2(s-8), bias in MFMA C-in), flat q-split,
// K/V double-buffered via global_load_lds, 16B-granule XOR swizzle.
// LDS-pipe-bound at ~90% of structural roofline (~91 us).
// ---------------------------------------------------------------------------
__global__ __launch_bounds__(256, 2) void flash_mfma(
    const _Float16* __restrict__ Qh_g, const _Float16* __restrict__ Kh_g,
    const _Float16* __restrict__ Vt_g, _Float16* __restrict__ Ao)
{
    __shared__ _Float16 Ksh[2][64][128];   // [buf][kv][d], granule-swizzled
    __shared__ _Float16 Vsh[2][128][64];   // [buf][d][kv], granule-swizzled
    __shared__ _Float16 Ps [128][64];      // [q][kv], granule-swizzled

    const int tid = threadIdx.x;
    const int wave = tid >> 6, lane = tid & 63;
    const int l15 = lane & 15, l4 = lane >> 4;
    const int qb = blockIdx.x, h = blockIdx.y, b = blockIdx.z;
    const int kh = h >> 2;
    const int key = l15 & 7;            // read-side swizzle key (row&7)

    // ---- Q fragments: direct fp16 loads (pre-scaled in gemm_qkv) ----
    h8 qf[2][4];
#pragma unroll
    for (int i = 0; i < 2; ++i) {
        const _Float16* qrow = Qh_g +
            (((size_t)b * H_ + h) * S_ + qb * 128 + wave * 32 + i * 16 + l15) * D_;
#pragma unroll
        for (int j = 0; j < 4; ++j)
            qf[i][j] = *(const h8*)(qrow + j * 32 + l4 * 8);
    }

    f4 o[2][8];
#pragma unroll
    for (int i = 0; i < 2; ++i)
#pragma unroll
        for (int t = 0; t < 8; ++t) o[i][t] = (f4){0.f, 0.f, 0.f, 0.f};
    float l_part[2] = {0.f, 0.f};

    const size_t kvoff = ((size_t)b * HK_ + kh) * S_ * D_;
    const _Float16* kg = Kh_g + kvoff;   // (S, D)
    const _Float16* vg = Vt_g + kvoff;   // (D, S)

    int krow[4], ksrc[4], vrow[4], vsrc[4];
#pragma unroll
    for (int t = 0; t < 4; ++t) {
        krow[t] = wave * 16 + t * 4 + (lane >> 4);            // kv row 0..63
        ksrc[t] = ((lane & 15) ^ (krow[t] & 7)) * 8;          // inv-swz col
        vrow[t] = wave * 32 + t * 8 + (lane >> 3);            // d row 0..127
        vsrc[t] = ((lane & 7) ^ (vrow[t] & 7)) * 8;           // inv-swz col
    }

    auto STAGE = [&](int bf, int kb) {
#pragma unroll
        for (int t = 0; t < 4; ++t)
            GLOAD16(kg + (size_t)(kb * 64 + krow[t]) * D_ + ksrc[t],
                    &Ksh[bf][wave * 16 + t * 4][0]);
#pragma unroll
        for (int t = 0; t < 4; ++t)
            GLOAD16(vg + (size_t)vrow[t] * S_ + kb * 64 + vsrc[t],
                    &Vsh[bf][wave * 32 + t * 8][0]);
    };

    STAGE(0, 0);
    int cur = 0;

    for (int kb = 0; kb < S_ / 64; ++kb) {
        __syncthreads();   // vmcnt(0): tile-kb stage landed; all prev reads done
        if (kb + 1 < S_ / 64) STAGE(cur ^ 1, kb + 1);   // overlaps this compute

        // ---- QK^T swapped: acc[c][i] -> q = l15 (+i*16), kv = c*16+l4*4+r ----
        f4 acc[4][2];
#pragma unroll
        for (int c = 0; c < 4; ++c)
#pragma unroll
            for (int i = 0; i < 2; ++i)
                acc[c][i] = (f4){-8.f, -8.f, -8.f, -8.f};   // exp2 bias in C-in
#pragma unroll
        for (int j = 0; j < 4; ++j) {
#pragma unroll
            for (int c = 0; c < 4; ++c) {
                h8 kf = *(const h8*)&Ksh[cur][c * 16 + l15][((j * 4 + l4) ^ key) * 8];
#pragma unroll
                for (int i = 0; i < 2; ++i)
                    acc[c][i] = __builtin_amdgcn_mfma_f32_16x16x32_f16(
                        kf, qf[i][j], acc[c][i], 0, 0, 0);
            }
        }

        // ---- exp2 + swizzled b64 P-store (rows wave-local, no barrier) ----
#pragma unroll
        for (int c = 0; c < 4; ++c) {
#pragma unroll
            for (int i = 0; i < 2; ++i) {
                h4 pk;
#pragma unroll
                for (int r = 0; r < 4; ++r) {
                    float e_ = exp2f(acc[c][i][r]);
                    l_part[i] += e_;
                    pk[r] = (_Float16)e_;
                }
                int g = 2 * c + (l4 >> 1);                    // 16B granule
                *(h4*)&Ps[wave * 32 + i * 16 + l15][(g ^ key) * 8 + (l4 & 1) * 4] = pk;
            }
        }

        // ---- PV ----
#pragma unroll
        for (int s2 = 0; s2 < 2; ++s2) {
            int gc = ((s2 * 4 + l4) ^ key) * 8;
            h8 pf0 = *(const h8*)&Ps[wave * 32 + l15][gc];
            h8 pf1 = *(const h8*)&Ps[wave * 32 + 16 + l15][gc];
#pragma unroll
            for (int t = 0; t < 8; ++t) {
                h8 vf = *(const h8*)&Vsh[cur][t * 16 + l15][gc];
                o[0][t] = __builtin_amdgcn_mfma_f32_16x16x32_f16(pf0, vf, o[0][t], 0, 0, 0);
                o[1][t] = __builtin_amdgcn_mfma_f32_16x16x32_f16(pf1, vf, o[1][t], 0, 0, 0);
            }
        }
        cur ^= 1;
    }

    // ---- softmax denominator (q = i*16 + l15), broadcast to C-layout rows ----
    float Linv[2];
#pragma unroll
    for (int i = 0; i < 2; ++i) {
        float l = l_part[i];
        l += __shfl_xor(l, 16);
        l += __shfl_xor(l, 32);
        Linv[i] = 1.f / l;
    }
#pragma unroll
    for (int i = 0; i < 2; ++i) {
        float inv[4];
#pragma unroll
        for (int r = 0; r < 4; ++r) inv[r] = __shfl(Linv[i], l4 * 4 + r);
#pragma unroll
        for (int t = 0; t < 8; ++t) {
#pragma unroll
            for (int r = 0; r < 4; ++r) {
                int row = qb * 128 + wave * 32 + i * 16 + l4 * 4 + r;
                Ao[((size_t)b * S_ + row) * (H_ * D_) + h * D_ + t * 16 + l15] =
                    (_Float16)(o[i][t][r] * inv[r]);
            }
        }
    }
}

// ---------------------------------------------------------------------------
extern "C" void kernel_launch(void* const* d_in, const int* in_sizes, int n_in,
                              void* d_out, int out_size, void* d_ws, size_t ws_size,
                              hipStream_t stream)
{
    const float* hidden  = (const float*)d_in[0];
    const float* cosT    = (const float*)d_in[1];
    const float* sinT    = (const float*)d_in[2];
    const float* w_qkv   = (const float*)d_in[3];
    const float* q_ln    = (const float*)d_in[4];
    const float* k_ln    = (const float*)d_in[5];
    const float* w_dense = (const float*)d_in[6];
    float* out = (float*)d_out;

    // workspace layout (bytes), NO aliasing (gemm_qkv writes Qh/Kh/Vt while
    // reading hidden16/wqkv16):
    //   attn16   : 16,777,216  @ 0
    //   hidden16 : 16,777,216  @ 16,777,216
    //   wqkv16   : 12,582,912  @ 33,554,432
    //   Qh       : 16,777,216  @ 46,137,344
    //   Kh       :  4,194,304  @ 62,914,560
    //   Vt       :  4,194,304  @ 67,108,864
    //   wdense16 :  8,388,608  @ 71,303,168
    // total 79,691,776
    char* w = (char*)d_ws;
    _Float16* attn16   = (_Float16*)w;
    _Float16* hidden16 = (_Float16*)(w + 16777216);
    _Float16* wqkv16   = (_Float16*)(w + 33554432);
    _Float16* Qh       = (_Float16*)(w + 46137344);
    _Float16* Kh       = (_Float16*)(w + 62914560);
    _Float16* Vt       = (_Float16*)(w + 67108864);
    _Float16* wdense16 = (_Float16*)(w + 71303168);

    // 0) fp32 -> fp16 operand conversions (single fused launch)
    cvt3<<<9216, 256, 0, stream>>>(hidden,  hidden16, 1048576,
                                   w_qkv,   wqkv16,   786432,
                                   w_dense, wdense16, 524288);

    // 1) QKV projection with fused RMSNorm+RoPE+V-transpose epilogue
    //    grid: 24 heads x 32 token-blocks of 128, 256 threads, 4 blocks/CU
    gemm_qkv<<<dim3(NH_, (B_ * S_) / 128), 256, 0, stream>>>(
        hidden16, wqkv16, cosT, sinT, q_ln, k_ln, Qh, Kh, Vt);

    // 2) MFMA flash attention -> attn16 (B,S,H*D) fp16  (single dispatch)
    flash_mfma<<<dim3(S_ / 128, H_, B_), 256, 0, stream>>>(Qh, Kh, Vt, attn16);

    // 3) dense projection (fp16 MFMA GEMM, fp32 out), 512 blocks = 2/CU
    gemm_dense<<<dim3(HID_ / 128, (B_ * S_) / 128), 256, 0, stream>>>(
        attn16, wdense16, out, B_ * S_, HID_, H_ * D_);
}